// Round 8
// baseline (34.669 us; speedup 1.0000x reference)
//
#include <hip/hip_runtime.h>

// ---------------------------------------------------------------------------
// TimeLSTMCell fused kernel for MI355X (gfx950) — round 10
// B=4096, D=256, U=512; out = concat(h, c_m) fp32
//
// ROUND 10: 8-phase-discipline port (T3-fine + T4 + T5) on the r5 geometry.
//   Evidence: all coarse levers flat (~33.5 +-1.5). Catalog: the escape from
//   the 2-phase plateau (MfmaUtil ~37%) is the fine phase schedule — per
//   sub-phase {ds_read cluster || stage-issue -> s_barrier -> lgkmcnt(0) ->
//   setprio(1) MFMA cluster -> setprio(0)}, counted vmcnt once per K-step
//   (never 0 until drain). Proven at 8 waves/block (m218b/m201: +21-41%);
//   4-wave port was null (m232) -> must ride the 128x64 / 512-thread / 1
//   blk/CU geometry (r5), where intra-block role-split REPLACES the
//   cross-block overlap that made coarse 1-blk/CU lose (r5/r7).
//   - prep: BK=64 tiles (r6 verbatim).
//   - main: 128x64 tile, 8 waves (2x4 of 64r x 16c), BK=64, 12 K-steps,
//     2 sub-phases/step (ks=0,1), 4 barriers/step, dbuf 112KB LDS.
//   - epilogue: r9 simplifications (tanhfast, NEG_EPS constant fold).
// ---------------------------------------------------------------------------

typedef __attribute__((ext_vector_type(8))) short short8_t;   // 8 bf16
typedef __attribute__((ext_vector_type(4))) float f32x4_t;
typedef unsigned int u32;

#define B_N 4096
#define D_K 256
#define U_N 512

__device__ __forceinline__ unsigned short f2bf(float f) {
    unsigned int x = __float_as_uint(f);
    unsigned int r = x + 0x7fffu + ((x >> 16) & 1u);   // RNE
    return (unsigned short)(r >> 16);
}

__device__ __forceinline__ float sigf(float z) {
    return 1.0f / (1.0f + __expf(-z));
}

// fast tanh: exact at +/-inf, ~1e-7 abs err
__device__ __forceinline__ float tanhfast(float z) {
    return 1.0f - 2.0f / (1.0f + __expf(2.0f * z));
}

__device__ __forceinline__ void gl16(const unsigned short* g, unsigned short* l) {
    __builtin_amdgcn_global_load_lds(
        (const __attribute__((address_space(1))) u32*)g,
        (__attribute__((address_space(3))) u32*)l, 16, 0, 0);
}

// swizzled element offset of (row r, k-chunk kc) inside a tile with 8 chunks/row
#define SWZ(r, kc) ((((r) * 8) + ((kc) ^ ((r) & 7))) * 8)

// counted vmcnt wait + scheduling fence (compile-time literal N)
#define WAIT_VM(N)                                            \
    asm volatile("s_waitcnt vmcnt(" #N ")" ::: "memory");     \
    __builtin_amdgcn_sched_barrier(0)

#define LGKM0                                                 \
    asm volatile("s_waitcnt lgkmcnt(0)" ::: "memory");        \
    __builtin_amdgcn_sched_barrier(0)

#define SBAR                                                  \
    __builtin_amdgcn_s_barrier();                             \
    __builtin_amdgcn_sched_barrier(0)

// ---------------------------------------------------------------------------
// prepass (r6 verbatim): 4 segments by flat chunk id (16B bf16 chunk each)
//   x  : 131072 chunks -> tiles (rb 0..31, kb 0..3)  of 128x64
//   h0 : 262144 chunks -> tiles (rb 0..31, kb 0..7)  of 128x64
//   ker:  81920 chunks -> tiles (nb 0..15, kb 0..3)  of 160x64 (transposed)
//   rk :  98304 chunks -> tiles (nb 0..15, kb 0..7)  of  96x64 (transposed)
// total 573440 chunks = 2240 blocks x 256
// ---------------------------------------------------------------------------
__global__ __launch_bounds__(256) void prep(
    const float* __restrict__ x, const float* __restrict__ h0,
    const float* __restrict__ kern, const float* __restrict__ rk,
    unsigned short* __restrict__ xs, unsigned short* __restrict__ hs,
    unsigned short* __restrict__ ksw, unsigned short* __restrict__ rsw)
{
    const int c = blockIdx.x * 256 + threadIdx.x;
    if (c < 131072) {                       // ---- x ----
        const int t = c >> 10, q = c & 1023;
        const int row = q >> 3, kc = q & 7;
        const int rb = t >> 2, kb = t & 3;
        const float* s = x + (size_t)(rb * 128 + row) * D_K + kb * 64 + kc * 8;
        short8_t o;
#pragma unroll
        for (int j = 0; j < 8; ++j) o[j] = (short)f2bf(s[j]);
        *reinterpret_cast<short8_t*>(xs + (size_t)t * 8192 + SWZ(row, kc)) = o;
    } else if (c < 393216) {                // ---- h0 ----
        const int c2 = c - 131072;
        const int t = c2 >> 10, q = c2 & 1023;
        const int row = q >> 3, kc = q & 7;
        const int rb = t >> 3, kb = t & 7;
        const float* s = h0 + (size_t)(rb * 128 + row) * U_N + kb * 64 + kc * 8;
        short8_t o;
#pragma unroll
        for (int j = 0; j < 8; ++j) o[j] = (short)f2bf(s[j]);
        *reinterpret_cast<short8_t*>(hs + (size_t)t * 8192 + SWZ(row, kc)) = o;
    } else if (c < 475136) {                // ---- kernel (transpose) ----
        const int c2 = c - 393216;
        const int t = c2 / 1280, q = c2 - t * 1280;
        const int kc = q / 160, r = q - kc * 160;     // r = mat*32 + cc
        const int nb = t >> 2, kb = t & 3;
        const int col = (r >> 5) * U_N + nb * 32 + (r & 31);
        short8_t o;
#pragma unroll
        for (int j = 0; j < 8; ++j)
            o[j] = (short)f2bf(kern[(size_t)(kb * 64 + kc * 8 + j) * 2560 + col]);
        *reinterpret_cast<short8_t*>(ksw + (size_t)t * 10240 + SWZ(r, kc)) = o;
    } else {                                // ---- rk (transpose) ----
        const int c2 = c - 475136;
        const int t = c2 / 768, q = c2 - t * 768;
        const int kc = q / 96, r = q - kc * 96;       // r = mat*32 + cc
        const int nb = t >> 3, kb = t & 7;
        const int col = (r >> 5) * U_N + nb * 32 + (r & 31);
        short8_t o;
#pragma unroll
        for (int j = 0; j < 8; ++j)
            o[j] = (short)f2bf(rk[(size_t)(kb * 64 + kc * 8 + j) * 1536 + col]);
        *reinterpret_cast<short8_t*>(rsw + (size_t)t * 6144 + SWZ(r, kc)) = o;
    }
}

// ---------------------------------------------------------------------------
// main fused kernel
// grid (8, 32) = 256 blocks (1/CU), 512 threads (8 waves, 2/SIMD)
// wave (wm, wn) = (wave>>2, wave&3): rows [64*wm,+64) x cols [16*wn,+16)
// of the 128x64 band, for every stacked gate matrix.
// B in LDS = two 32-col prep tiles stacked: phase1 2x160 rows, phase2 2x96.
// K-step: {stage(s+1); vmcnt(L); SBAR; [phase ks0][phase ks1]; SBAR}
// phase ks: {9|7 ds_read_b128 -> SBAR -> lgkmcnt(0) -> setprio(1) 20|12 MFMA}
// ---------------------------------------------------------------------------
__global__ __launch_bounds__(512, 2) void tlstm_main(
    const unsigned short* __restrict__ xs,    // swizzled x tiles
    const unsigned short* __restrict__ hs,    // swizzled h0 tiles
    const unsigned short* __restrict__ ksw,   // swizzled kernel^T tiles
    const unsigned short* __restrict__ rsw,   // swizzled rk^T tiles
    const float* __restrict__ tvec,           // [4096]
    const float* __restrict__ c0,             // [4096][512]
    const float* __restrict__ ktime,          // [1536] cols [t1,t2,o]
    float* __restrict__ out)                  // h, then c_m
{
    // per buffer: A 8192 elems (16KB) + B 20480 elems (40KB) = 56KB; x2 = 112KB
    __shared__ __align__(16) unsigned short lds[2][28672];

    const int tid = threadIdx.x;
    const int wave = tid >> 6;
    const int lane = tid & 63;
    const int lr = lane & 15;
    const int lq = lane >> 4;
    const int wm = wave >> 2;                 // 0..1 : 64-row half
    const int wn = wave & 3;                  // 0..3 : 16-col slice
    const int nb = blockIdx.x;                // 0..7  (64-col blocks)
    const int rb = blockIdx.y;                // 0..31 (128-row blocks)

    const int u = nb * 64 + wn * 16 + lr;     // output column

    // acc[m][p]: gate m (0..4 = x@K, 5..7 = h0@RK), row frag p (wm*64+p*16)
    f32x4_t acc[8][4];
#pragma unroll
    for (int m = 0; m < 8; ++m)
#pragma unroll
        for (int p = 0; p < 4; ++p)
            acc[m][p] = (f32x4_t){0.f, 0.f, 0.f, 0.f};

    // ---- staging (r5 verbatim): linear global_load_lds ----
    // per-thread vmem ops: phase1 (s<4): 2 A + 5 B = 7; phase2: 2 A + 3 B = 5
    auto stage = [&](int s, int buf) {
        unsigned short* ab = &lds[buf][0];
        unsigned short* bb = &lds[buf][8192];
        if (s < 4) {
            const unsigned short* at = xs + (size_t)(rb * 4 + s) * 8192;
            gl16(at + (size_t)tid * 8,         ab + (size_t)(wave * 64) * 8);
            gl16(at + (size_t)(512 + tid) * 8, ab + (size_t)(512 + wave * 64) * 8);
            const unsigned short* b0 = ksw + (size_t)(nb * 8 + s) * 10240;
            const unsigned short* b1 = ksw + (size_t)(nb * 8 + 4 + s) * 10240;
#pragma unroll
            for (int j = 0; j < 5; ++j) {
                const int c = j * 512 + tid;            // 0..2559; 1280 wave-aligned
                const unsigned short* src = (c < 1280) ? (b0 + (size_t)c * 8)
                                                       : (b1 + (size_t)(c - 1280) * 8);
                gl16(src, bb + (size_t)(j * 512 + wave * 64) * 8);
            }
        } else {
            const unsigned short* at = hs + (size_t)(rb * 8 + (s - 4)) * 8192;
            gl16(at + (size_t)tid * 8,         ab + (size_t)(wave * 64) * 8);
            gl16(at + (size_t)(512 + tid) * 8, ab + (size_t)(512 + wave * 64) * 8);
            const unsigned short* b0 = rsw + (size_t)(nb * 16 + (s - 4)) * 6144;
            const unsigned short* b1 = rsw + (size_t)(nb * 16 + 8 + (s - 4)) * 6144;
#pragma unroll
            for (int j = 0; j < 3; ++j) {
                const int c = j * 512 + tid;            // 0..1535; 768 wave-aligned
                const unsigned short* src = (c < 768) ? (b0 + (size_t)c * 8)
                                                      : (b1 + (size_t)(c - 768) * 8);
                gl16(src, bb + (size_t)(j * 512 + wave * 64) * 8);
            }
        }
    };

    // ---- phase bodies: ds_read cluster -> SBAR -> lgkm(0) -> prio MFMA ----
    auto phase1 = [&](int buf, int ks) {    // x @ kernel, one BK=32 slice
        const unsigned short* ab = &lds[buf][0];
        const unsigned short* bb = &lds[buf][8192];
        const int kc = ks * 4 + lq;
        short8_t a[4], b[5];
#pragma unroll
        for (int p = 0; p < 4; ++p)
            a[p] = *reinterpret_cast<const short8_t*>(ab + SWZ(wm * 64 + p * 16 + lr, kc));
#pragma unroll
        for (int m = 0; m < 5; ++m) {
            const int r = (wn >> 1) * 160 + m * 32 + (wn & 1) * 16 + lr;
            b[m] = *reinterpret_cast<const short8_t*>(bb + SWZ(r, kc));
        }
        __builtin_amdgcn_sched_barrier(0);
        SBAR;                              // role-split: reads vs MFMA phases
        LGKM0;
        __builtin_amdgcn_s_setprio(1);
#pragma unroll
        for (int m = 0; m < 5; ++m)
#pragma unroll
            for (int p = 0; p < 4; ++p)
                acc[m][p] = __builtin_amdgcn_mfma_f32_16x16x32_bf16(a[p], b[m], acc[m][p], 0, 0, 0);
        __builtin_amdgcn_s_setprio(0);
        __builtin_amdgcn_sched_barrier(0);
    };

    auto phase2 = [&](int buf, int ks) {    // h0 @ rk, one BK=32 slice
        const unsigned short* ab = &lds[buf][0];
        const unsigned short* bb = &lds[buf][8192];
        const int kc = ks * 4 + lq;
        short8_t a[4], b[3];
#pragma unroll
        for (int p = 0; p < 4; ++p)
            a[p] = *reinterpret_cast<const short8_t*>(ab + SWZ(wm * 64 + p * 16 + lr, kc));
#pragma unroll
        for (int m = 0; m < 3; ++m) {
            const int r = (wn >> 1) * 96 + m * 32 + (wn & 1) * 16 + lr;
            b[m] = *reinterpret_cast<const short8_t*>(bb + SWZ(r, kc));
        }
        __builtin_amdgcn_sched_barrier(0);
        SBAR;
        LGKM0;
        __builtin_amdgcn_s_setprio(1);
#pragma unroll
        for (int m = 0; m < 3; ++m)
#pragma unroll
            for (int p = 0; p < 4; ++p)
                acc[5 + m][p] = __builtin_amdgcn_mfma_f32_16x16x32_bf16(a[p], b[m], acc[5 + m][p], 0, 0, 0);
        __builtin_amdgcn_s_setprio(0);
        __builtin_amdgcn_sched_barrier(0);
    };

    // step S: (stage(S+1) already issued) wait tile S, barrier, two phases,
    // trailing barrier releases buffer S&1 for stage(S+2).
#define K_BODY(S, NV, PH)                                  \
    {                                                      \
        WAIT_VM(NV);                                       \
        SBAR;                                              \
        PH((S) & 1, 0);                                    \
        PH((S) & 1, 1);                                    \
        SBAR;                                              \
    }

    // ---- pipelined K-loop: 12 steps, per-thread L = [7,7,7,7,5 x8] ----
    stage(0, 0);
    stage(1, 1);   K_BODY(0, 7, phase1);
    stage(2, 0);   K_BODY(1, 7, phase1);
    stage(3, 1);   K_BODY(2, 7, phase1);
    stage(4, 0);   K_BODY(3, 5, phase1);
    stage(5, 1);   K_BODY(4, 5, phase2);
    stage(6, 0);   K_BODY(5, 5, phase2);
    stage(7, 1);   K_BODY(6, 5, phase2);
    stage(8, 0);   K_BODY(7, 5, phase2);
    stage(9, 1);   K_BODY(8, 5, phase2);
    stage(10, 0);  K_BODY(9, 5, phase2);
    stage(11, 1);  K_BODY(10, 5, phase2);
    K_BODY(11, 0, phase2);

    // ---- epilogue: TimeLSTM elementwise (fp32) ----
    // t1_constraint: sigmoid output is always > -1e-5 -> constant -1e-5.
    const float NEG_EPS = -1e-5f;
    const float kt1 = ktime[u];
    const float kt2 = ktime[U_N + u];
    const float kto = ktime[2 * U_N + u];
#pragma unroll
    for (int p = 0; p < 4; ++p)
#pragma unroll
        for (int i2 = 0; i2 < 4; ++i2) {
            const int b = rb * 128 + wm * 64 + p * 16 + lq * 4 + i2;
            const float tb = tvec[b];
            const float c0v = c0[(size_t)b * U_N + u];
            const float x_i  = acc[0][p][i2];
            const float x_c  = acc[1][p][i2];
            const float x_o  = acc[2][p][i2];
            const float x_t1 = acc[3][p][i2];
            const float x_t2 = acc[4][p][i2];
            const float r_i  = acc[5][p][i2];
            const float r_c  = acc[6][p][i2];
            const float r_o  = acc[7][p][i2];

            const float ig  = sigf(x_i + r_i);
            const float t1v = sigf(x_t1 + sigf(tb * kt1));
            const float t2v = sigf(x_t2 + sigf(tb * kt2));
            const float ct  = tanhfast(x_c + r_c);
            const float cm_ = (1.f - ig * t1v) * c0v + ig * ct * NEG_EPS;
            const float cm  = (1.f - ig) * c0v + ig * ct * t2v;
            const float og  = sigf(x_o + r_o + tb * kto);

            out[(size_t)b * U_N + u] = tanhfast(cm_) * og;
            out[(size_t)B_N * U_N + (size_t)b * U_N + u] = cm;
        }
}

// ---------------------------------------------------------------------------
extern "C" void kernel_launch(void* const* d_in, const int* in_sizes, int n_in,
                              void* d_out, int out_size, void* d_ws, size_t ws_size,
                              hipStream_t stream) {
    const float* x     = (const float*)d_in[0];   // [4096][256]
    const float* t     = (const float*)d_in[1];   // [4096][1]
    const float* h0    = (const float*)d_in[2];   // [4096][512]
    const float* c0    = (const float*)d_in[3];   // [4096][512]
    const float* kern  = (const float*)d_in[4];   // [256][2560]
    const float* rk    = (const float*)d_in[5];   // [512][1536]
    const float* ktime = (const float*)d_in[6];   // [1][1536]
    float* out = (float*)d_out;

    // ws layout (bytes):
    //   xs  @ 0        : 4096*256*2  = 2,097,152  (swizzled 128x64 tiles)
    //   hs  @ 2097152  : 4096*512*2  = 4,194,304
    //   ksw @ 6291456  : 2560*256*2  = 1,310,720  (swizzled 160x64 tiles)
    //   rsw @ 7602176  : 1536*512*2  = 1,572,864  (swizzled  96x64 tiles)
    unsigned short* xs  = (unsigned short*)d_ws;
    unsigned short* hs  = (unsigned short*)((char*)d_ws + 2097152);
    unsigned short* ksw = (unsigned short*)((char*)d_ws + 6291456);
    unsigned short* rsw = (unsigned short*)((char*)d_ws + 7602176);

    prep<<<2240, 256, 0, stream>>>(x, h0, kern, rk, xs, hs, ksw, rsw);
    tlstm_main<<<dim3(8, 32), 512, 0, stream>>>(
        xs, hs, ksw, rsw, t, c0, ktime, out);
}